// Round 6
// baseline (122.633 us; speedup 1.0000x reference)
//
#include <hip/hip_runtime.h>

// SemanticRenderer: out[r, c] = sum_{i: ray_indices[i]==r} weights[i] * semantics[i, c]
// semantics: [N, 32] f32, weights: [N] f32, ray_indices: [N] int32 (SORTED), out: [R, 32] f32
//
// Pass 0: memset seg[] (int2 per ray) to 0 -> empty rays have start==end==0.
// Pass 1 (bounds): int4-vectorized scan of ridx; run boundaries write seg[ray].
// Pass 2 (render): PERSISTENT grid (2048 blocks = 32 waves/CU exactly); each
//   wave grid-strides over rays (1 ray at a time, ~16 rays/wave). Next ray's
//   seg bounds prefetched one iteration ahead (hides the only dependent load).
//   lane = 8*g + q; a load step covers 8 rows x 128B = 1 KiB coalesced;
//   4/2/1-deep drain ladder; NT hints on the zero-reuse sem/w/out streams.

typedef float f32x4 __attribute__((ext_vector_type(4)));

__global__ __launch_bounds__(256) void sr_bounds_kernel(
    const int* __restrict__ ridx, int2* __restrict__ seg, int N)
{
    const int t  = blockIdx.x * blockDim.x + threadIdx.x;
    const int i4 = t * 4;
    if (i4 >= N) return;

    if (i4 + 4 <= N) {
        const int4 v = *reinterpret_cast<const int4*>(ridx + i4);
        const int prev = (i4 == 0) ? -1 : ridx[i4 - 1];
        const int tail = (i4 + 4 < N) ? ridx[i4 + 4] : -2;   // -2 matches no ray id
        if (v.x != prev) { seg[v.x].x = i4;     if (prev >= 0) seg[prev].y = i4; }
        if (v.y != v.x)  { seg[v.y].x = i4 + 1; seg[v.x].y = i4 + 1; }
        if (v.z != v.y)  { seg[v.z].x = i4 + 2; seg[v.y].y = i4 + 2; }
        if (v.w != v.z)  { seg[v.w].x = i4 + 3; seg[v.z].y = i4 + 3; }
        if (v.w != tail) { seg[v.w].y = i4 + 4; }
    } else {
        for (int i = i4; i < N; ++i) {
            const int r    = ridx[i];
            const int prev = (i == 0) ? -1 : ridx[i - 1];
            const int next = (i == N - 1) ? -2 : ridx[i + 1];
            if (r != prev) seg[r].x = i;
            if (r != next) seg[r].y = i + 1;
        }
    }
}

__global__ __launch_bounds__(256) void SemanticRenderer_70205535421052_kernel(
    const f32x4* __restrict__ sem4,    // [N*8] (N rows of 8 float4)
    const float* __restrict__ w,       // [N]
    const int2*  __restrict__ seg,     // [R] (start, end); start==end for empty
    f32x4*       __restrict__ out4,    // [R*8]
    int R)
{
    const int wave = threadIdx.x >> 6;
    const int lane = threadIdx.x & 63;
    const int q    = lane & 7;         // class quad (classes 4q..4q+3)
    const int g    = lane >> 3;        // sample subgroup 0..7
    const int nw   = gridDim.x * 4;    // total waves (persistent)
    int r = blockIdx.x * 4 + wave;
    if (r >= R) return;

    int2 se_next = seg[r];             // prefetch for first iteration

    while (true) {
        const int2 se = se_next;
        const int  rn = r + nw;
        if (rn < R) se_next = seg[rn]; // prefetch next ray's bounds (hidden
                                       // behind this ray's streaming)
        int s = se.x + g;
        const int e = se.y;
        f32x4 acc = (f32x4)0.f;

        // 4-deep: four independent 1 KiB wave-loads in flight
        for (; s + 24 < e; s += 32) {
            const float w0 = __builtin_nontemporal_load(w + s);
            const float w1 = __builtin_nontemporal_load(w + s + 8);
            const float w2 = __builtin_nontemporal_load(w + s + 16);
            const float w3 = __builtin_nontemporal_load(w + s + 24);
            const f32x4 v0 = __builtin_nontemporal_load(sem4 + (size_t)s * 8 + q);
            const f32x4 v1 = __builtin_nontemporal_load(sem4 + (size_t)(s + 8)  * 8 + q);
            const f32x4 v2 = __builtin_nontemporal_load(sem4 + (size_t)(s + 16) * 8 + q);
            const f32x4 v3 = __builtin_nontemporal_load(sem4 + (size_t)(s + 24) * 8 + q);
            acc += w0 * v0; acc += w1 * v1; acc += w2 * v2; acc += w3 * v3;
        }
        for (; s + 8 < e; s += 16) {
            const float w0 = __builtin_nontemporal_load(w + s);
            const float w1 = __builtin_nontemporal_load(w + s + 8);
            const f32x4 v0 = __builtin_nontemporal_load(sem4 + (size_t)s * 8 + q);
            const f32x4 v1 = __builtin_nontemporal_load(sem4 + (size_t)(s + 8) * 8 + q);
            acc += w0 * v0; acc += w1 * v1;
        }
        if (s < e) {
            const float w0 = __builtin_nontemporal_load(w + s);
            const f32x4 v0 = __builtin_nontemporal_load(sem4 + (size_t)s * 8 + q);
            acc += w0 * v0;
        }

        // reduce across the 8 sample subgroups (lane bits 3,4,5); wave = 64
        #pragma unroll
        for (int m = 8; m < 64; m <<= 1) {
            acc.x += __shfl_xor(acc.x, m, 64);
            acc.y += __shfl_xor(acc.y, m, 64);
            acc.z += __shfl_xor(acc.z, m, 64);
            acc.w += __shfl_xor(acc.w, m, 64);
        }

        if (g == 0)
            __builtin_nontemporal_store(acc, out4 + (size_t)r * 8 + q);

        if (rn >= R) break;
        r = rn;
    }
}

extern "C" void kernel_launch(void* const* d_in, const int* in_sizes, int n_in,
                              void* d_out, int out_size, void* d_ws, size_t ws_size,
                              hipStream_t stream) {
    const f32x4* sem4 = (const f32x4*)d_in[0];
    const float* w    = (const float*)d_in[1];
    const int*   ridx = (const int*)d_in[2];
    f32x4*       out4 = (f32x4*)d_out;

    const int N = in_sizes[1];        // number of samples (weights is [N])
    const int R = out_size / 32;      // number of rays (out is [R,32])

    int2* seg = (int2*)d_ws;          // [R] (start, end)

    // start==end==0 for rays never written (empty) -> loop skipped -> zeros stored
    hipMemsetAsync(seg, 0, (size_t)R * sizeof(int2), stream);

    const int bthreads = (N + 3) / 4;
    sr_bounds_kernel<<<(bthreads + 255) / 256, 256, 0, stream>>>(ridx, seg, N);

    // persistent: 2048 blocks x 4 waves = 8192 waves = 32 waves/CU on 256 CUs
    int blocks = 2048;
    const int needed = (R + 3) / 4;
    if (needed < blocks) blocks = needed;
    SemanticRenderer_70205535421052_kernel<<<blocks, 256, 0, stream>>>(
        sem4, w, seg, out4, R);
}